// Round 4
// baseline (225.623 us; speedup 1.0000x reference)
//
#include <hip/hip_runtime.h>
#include <cstdint>
#include <cstddef>

// ConcreteLayer forward: softmax((W + gumbel(U))/T, axis=1); out = x @ samples.
// B=4096, IN=4096, OUT=1024. bf16 MFMA GEMM path.
// ws: xb (bf16 x, 32MB) | bt (bf16 samples^T [OUT,IN], 8MB) | stats (4096 float2)

#define TINYF 1.17549435082228750797e-38f
#define LN2F 0.69314718055994530942f
#define LOG2EF 1.44269504088896340736f

typedef unsigned short u16;
typedef __attribute__((ext_vector_type(8))) short bf16x8;
typedef __attribute__((ext_vector_type(4))) float f32x4;

__device__ __forceinline__ u16 f2bf(float f) {
  union { float f; uint32_t u; } v; v.f = f;
  uint32_t r = v.u + 0x7FFFu + ((v.u >> 16) & 1u);  // RNE
  return (u16)(r >> 16);
}

// hardware transcendentals: v_log_f32 = log2, v_exp_f32 = 2^x
__device__ __forceinline__ float log2_hw(float x) { return __builtin_amdgcn_logf(x); }
__device__ __forceinline__ float exp2_hw(float x) { return __builtin_amdgcn_exp2f(x); }

// g = -ln(-ln(u)) = -ln2 * log2(ln2 * (-log2 u))
__device__ __forceinline__ float gumbel_fast(float u) {
  float t = -log2_hw(u);                 // -log2(u) > 0
  return -LN2F * log2_hw(t * LN2F);
}
__device__ __forceinline__ float exp_fast(float x) { return exp2_hw(x * LOG2EF); }

__device__ __forceinline__ void gld_lds16(const void* g, void* l) {
  __builtin_amdgcn_global_load_lds(
      (__attribute__((address_space(1))) void*)(g),
      (__attribute__((address_space(3))) void*)(l), 16, 0, 0);
}

// ---------------- kernel 1: x fp32 -> bf16, fused with zeroing d_out ----------------
__global__ void cast_zero_kernel(const float4* __restrict__ x, ushort4* __restrict__ xb,
                                 float4* __restrict__ out, int n4x, int n4o) {
  int i = blockIdx.x * blockDim.x + threadIdx.x;
  if (i < n4x) {
    float4 v = x[i];
    ushort4 o;
    o.x = f2bf(v.x); o.y = f2bf(v.y); o.z = f2bf(v.z); o.w = f2bf(v.w);
    xb[i] = o;
  } else {
    int j = i - n4x;
    if (j < n4o) out[j] = make_float4(0.f, 0.f, 0.f, 0.f);
  }
}

// ---------------- kernel 2: per-row softmax stats (max, sumexp), float4 loads ----------------
__global__ void softmax_stats_kernel(const float4* __restrict__ W4, const float4* __restrict__ U4,
                                     const float* __restrict__ Tp, float2* __restrict__ stats) {
  const int row = blockIdx.x;
  const int t = threadIdx.x;              // 256 threads, 1024 cols -> 1 float4 each
  const float invT = 1.0f / Tp[0];
  size_t gi = (size_t)row * 256 + t;
  float4 w = W4[gi], u = U4[gi];
  float lg[4];
  lg[0] = (w.x + gumbel_fast(u.x * (1.0f - TINYF) + TINYF)) * invT;
  lg[1] = (w.y + gumbel_fast(u.y * (1.0f - TINYF) + TINYF)) * invT;
  lg[2] = (w.z + gumbel_fast(u.z * (1.0f - TINYF) + TINYF)) * invT;
  lg[3] = (w.w + gumbel_fast(u.w * (1.0f - TINYF) + TINYF)) * invT;
  float m = fmaxf(fmaxf(lg[0], lg[1]), fmaxf(lg[2], lg[3]));
#pragma unroll
  for (int o = 32; o > 0; o >>= 1) m = fmaxf(m, __shfl_down(m, o));
  __shared__ float redm[4], reds[4];
  if ((t & 63) == 0) redm[t >> 6] = m;
  __syncthreads();
  m = fmaxf(fmaxf(redm[0], redm[1]), fmaxf(redm[2], redm[3]));
  float s = exp_fast(lg[0] - m) + exp_fast(lg[1] - m) + exp_fast(lg[2] - m) + exp_fast(lg[3] - m);
#pragma unroll
  for (int o = 32; o > 0; o >>= 1) s += __shfl_down(s, o);
  if ((t & 63) == 0) reds[t >> 6] = s;
  __syncthreads();
  if (t == 0) stats[row] = make_float2(m, reds[0] + reds[1] + reds[2] + reds[3]);
}

// ---------------- kernel 3: normalize + transpose -> bf16 samples^T [OUT,IN] ----------------
__global__ void norm_transpose_kernel(const float* __restrict__ W, const float* __restrict__ U,
                                      const float* __restrict__ Tp, const float2* __restrict__ stats,
                                      u16* __restrict__ BT) {
  __shared__ float tile[64][65];
  const int k0 = blockIdx.x * 64, n0 = blockIdx.y * 64;
  const int t = threadIdx.x;
  const float invT = 1.0f / Tp[0];
  {
    const int nn4 = (t & 15) * 4, kq = t >> 4;   // 16 rows per pass, float4 cols
#pragma unroll
    for (int r = 0; r < 4; ++r) {
      int kk = r * 16 + kq;
      size_t gi = (size_t)(k0 + kk) * 1024 + (n0 + nn4);
      float4 w = *(const float4*)&W[gi];
      float4 u = *(const float4*)&U[gi];
      float2 st = stats[k0 + kk];
      float rs = 1.0f / st.y;
      tile[kk][nn4 + 0] = exp_fast((w.x + gumbel_fast(u.x * (1.0f - TINYF) + TINYF)) * invT - st.x) * rs;
      tile[kk][nn4 + 1] = exp_fast((w.y + gumbel_fast(u.y * (1.0f - TINYF) + TINYF)) * invT - st.x) * rs;
      tile[kk][nn4 + 2] = exp_fast((w.z + gumbel_fast(u.z * (1.0f - TINYF) + TINYF)) * invT - st.x) * rs;
      tile[kk][nn4 + 3] = exp_fast((w.w + gumbel_fast(u.w * (1.0f - TINYF) + TINYF)) * invT - st.x) * rs;
    }
  }
  __syncthreads();
  {
    const int kk4 = (t & 15) * 4, nq = t >> 4;
#pragma unroll
    for (int r = 0; r < 4; ++r) {
      int nn = r * 16 + nq;
      ushort4 o;
      o.x = f2bf(tile[kk4 + 0][nn]);
      o.y = f2bf(tile[kk4 + 1][nn]);
      o.z = f2bf(tile[kk4 + 2][nn]);
      o.w = f2bf(tile[kk4 + 3][nn]);
      *(ushort4*)&BT[(size_t)(n0 + nn) * 4096 + (k0 + kk4)] = o;
    }
  }
}

// ---------------- kernel 4: GEMM 128x128 tile, 4 waves a 64x64, split-K=4, atomic epilogue ----------------
#define TM 128
#define TN 128
#define TK 32
#define SPLITK 4

__launch_bounds__(256)
__global__ void gemm_bt_kernel(const u16* __restrict__ A, const u16* __restrict__ BT,
                               float* __restrict__ C, int M, int N, int K) {
  __shared__ u16 As[TM * TK];  // 8 KB, unpadded (global_load_lds lane-contiguous)
  __shared__ u16 Bs[TN * TK];  // 8 KB

  const int tid = threadIdx.x;
  const int lane = tid & 63, w = tid >> 6;
  const int wm = w >> 1, wn = w & 1;           // 2x2 wave grid, 64x64 per wave
  const int m0 = blockIdx.x * TM, n0 = blockIdx.y * TN;
  const int quad = lane >> 4, r16 = lane & 15;
  const int lrow = lane >> 2;                  // staging row within 16-row chunk
  const int lk = (lane & 3) * 8;               // staging bf16 col offset

  const int kz = blockIdx.z;                   // split-K
  const int Kq = K / SPLITK;
  const u16* Ak = A + (size_t)kz * Kq;
  const u16* Bk = BT + (size_t)kz * Kq;

  f32x4 acc[4][4] = {};

  for (int kt = 0; kt < Kq; kt += TK) {
    __syncthreads();
#pragma unroll
    for (int c = 0; c < 2; ++c) {
      int chunk = w * 2 + c;                   // 0..7 -> 16 rows each
      gld_lds16(Ak + (size_t)(m0 + chunk * 16 + lrow) * K + kt + lk, (char*)As + chunk * 1024);
    }
#pragma unroll
    for (int c = 0; c < 2; ++c) {
      int chunk = w * 2 + c;
      gld_lds16(Bk + (size_t)(n0 + chunk * 16 + lrow) * K + kt + lk, (char*)Bs + chunk * 1024);
    }
    __syncthreads();

    bf16x8 aF[4], bF[4];
#pragma unroll
    for (int mi = 0; mi < 4; ++mi)
      aF[mi] = *(const bf16x8*)&As[(wm * 64 + mi * 16 + r16) * TK + quad * 8];
#pragma unroll
    for (int ni = 0; ni < 4; ++ni)
      bF[ni] = *(const bf16x8*)&Bs[(wn * 64 + ni * 16 + r16) * TK + quad * 8];
#pragma unroll
    for (int mi = 0; mi < 4; ++mi)
#pragma unroll
      for (int ni = 0; ni < 4; ++ni)
        acc[mi][ni] = __builtin_amdgcn_mfma_f32_16x16x32_bf16(aF[mi], bF[ni], acc[mi][ni], 0, 0, 0);
  }

  // epilogue: C/D layout col = lane&15, row = quad*4 + reg; accumulate across split-K
#pragma unroll
  for (int mi = 0; mi < 4; ++mi)
#pragma unroll
    for (int ni = 0; ni < 4; ++ni)
#pragma unroll
      for (int r = 0; r < 4; ++r) {
        int row = m0 + wm * 64 + mi * 16 + quad * 4 + r;
        int col = n0 + wn * 64 + ni * 16 + r16;
        atomicAdd(&C[(size_t)row * N + col], acc[mi][ni][r]);
      }
}

extern "C" void kernel_launch(void* const* d_in, const int* in_sizes, int n_in,
                              void* d_out, int out_size, void* d_ws, size_t ws_size,
                              hipStream_t stream) {
  const int M = 4096, K = 4096, N = 1024;  // B, IN, OUT
  const float* x = (const float*)d_in[0];
  const float* W = (const float*)d_in[1];
  const float* U = (const float*)d_in[2];
  const float* Tp = (const float*)d_in[3];
  float* out = (float*)d_out;

  char* ws = (char*)d_ws;
  u16* xb = (u16*)ws;                                          // 32 MB
  u16* bt = (u16*)(ws + (size_t)M * K * 2);                    // 8 MB
  float2* stats = (float2*)(ws + (size_t)M * K * 2 + (size_t)N * K * 2);

  const int n4x = M * K / 4, n4o = M * N / 4;
  cast_zero_kernel<<<dim3((n4x + n4o) / 256), 256, 0, stream>>>(
      (const float4*)x, (ushort4*)xb, (float4*)out, n4x, n4o);
  softmax_stats_kernel<<<dim3(K), 256, 0, stream>>>((const float4*)W, (const float4*)U, Tp, stats);
  norm_transpose_kernel<<<dim3(K / 64, N / 64), 256, 0, stream>>>(W, U, Tp, stats, bt);
  gemm_bt_kernel<<<dim3(M / TM, N / TN, SPLITK), 256, 0, stream>>>(xb, bt, out, M, N, K);
}

// Round 5
// 196.570 us; speedup vs baseline: 1.1478x; 1.1478x over previous
//
#include <hip/hip_runtime.h>
#include <cstdint>
#include <cstddef>

// ConcreteLayer forward: out = x @ softmax_rows((W + gumbel(U))/T)
// Reformulated: d_i = sum_k exp(l_ik);  out = (x * (1/d)^T_broadcast) @ exp(l)
//   (max-subtraction dropped: l <= ~18, exp fits fp32; folds exactly into d)
// B=4096, IN=4096, OUT=1024. bf16 MFMA GEMM.
// ws: xb (bf16 x', 32MB) | bt (bf16 exp(l)^T [OUT,IN], 8MB) | d (4096 f32 row sums)

#define TINYF 1.17549435082228750797e-38f
#define LN2F 0.69314718055994530942f
#define LOG2EF 1.44269504088896340736f

typedef unsigned short u16;
typedef __attribute__((ext_vector_type(8))) short bf16x8;
typedef __attribute__((ext_vector_type(4))) float f32x4;

__device__ __forceinline__ u16 f2bf(float f) {
  union { float f; uint32_t u; } v; v.f = f;
  uint32_t r = v.u + 0x7FFFu + ((v.u >> 16) & 1u);  // RNE
  return (u16)(r >> 16);
}

__device__ __forceinline__ float log2_hw(float x) { return __builtin_amdgcn_logf(x); }
__device__ __forceinline__ float exp2_hw(float x) { return __builtin_amdgcn_exp2f(x); }

// g = -ln(-ln(u)) = -ln2 * log2(ln2 * (-log2 u))
__device__ __forceinline__ float gumbel_fast(float u) {
  float t = -log2_hw(u);
  return -LN2F * log2_hw(t * LN2F);
}
__device__ __forceinline__ float exp_fast(float x) { return exp2_hw(x * LOG2EF); }

__device__ __forceinline__ void gld_lds16(const void* g, void* l) {
  __builtin_amdgcn_global_load_lds(
      (__attribute__((address_space(1))) void*)(g),
      (__attribute__((address_space(3))) void*)(l), 16, 0, 0);
}

// ---------------- kernel 1: exp-transpose + row-sum accumulate ----------------
// Per 64x64 tile of l: e = exp((W+G)/T); write e^T as bf16 to BT; atomicAdd row sums to d.
__global__ void trans_exp_kernel(const float* __restrict__ W, const float* __restrict__ U,
                                 const float* __restrict__ Tp, u16* __restrict__ BT,
                                 float* __restrict__ d) {
  __shared__ float tile[64][65];
  const int k0 = blockIdx.x * 64, n0 = blockIdx.y * 64;
  const int t = threadIdx.x;
  const float invT = 1.0f / Tp[0];
  {
    const int nn4 = (t & 15) * 4, kq = t >> 4;   // 16 rows per pass, float4 cols
#pragma unroll
    for (int r = 0; r < 4; ++r) {
      int kk = r * 16 + kq;
      size_t gi = (size_t)(k0 + kk) * 1024 + (n0 + nn4);
      float4 w = *(const float4*)&W[gi];
      float4 u = *(const float4*)&U[gi];
      float e0 = exp_fast((w.x + gumbel_fast(u.x * (1.0f - TINYF) + TINYF)) * invT);
      float e1 = exp_fast((w.y + gumbel_fast(u.y * (1.0f - TINYF) + TINYF)) * invT);
      float e2 = exp_fast((w.z + gumbel_fast(u.z * (1.0f - TINYF) + TINYF)) * invT);
      float e3 = exp_fast((w.w + gumbel_fast(u.w * (1.0f - TINYF) + TINYF)) * invT);
      tile[kk][nn4 + 0] = e0; tile[kk][nn4 + 1] = e1;
      tile[kk][nn4 + 2] = e2; tile[kk][nn4 + 3] = e3;
      // partial row sum over this thread's 4 cols; reduce across the 16 lanes sharing kk
      float s = (e0 + e1) + (e2 + e3);
#pragma unroll
      for (int m = 8; m > 0; m >>= 1) s += __shfl_xor(s, m, 16);
      if ((t & 15) == 0) atomicAdd(&d[k0 + kk], s);
    }
  }
  __syncthreads();
  {
    const int kk4 = (t & 15) * 4, nq = t >> 4;
#pragma unroll
    for (int r = 0; r < 4; ++r) {
      int nn = r * 16 + nq;
      ushort4 o;
      o.x = f2bf(tile[kk4 + 0][nn]);
      o.y = f2bf(tile[kk4 + 1][nn]);
      o.z = f2bf(tile[kk4 + 2][nn]);
      o.w = f2bf(tile[kk4 + 3][nn]);
      *(ushort4*)&BT[(size_t)(n0 + nn) * 4096 + (k0 + kk4)] = o;
    }
  }
}

// ---------------- kernel 2: x' = x / d (bf16), fused with zeroing d_out ----------------
__global__ void cast_zero_kernel(const float4* __restrict__ x, const float4* __restrict__ d4,
                                 ushort4* __restrict__ xb, float4* __restrict__ out,
                                 int n4x, int n4o) {
  int i = blockIdx.x * blockDim.x + threadIdx.x;
  if (i < n4x) {
    int col4 = i & 1023;                 // 1024 float4 per x-row; col index into d
    float4 v = x[i];
    float4 dd = d4[col4];
    ushort4 o;
    o.x = f2bf(v.x / dd.x); o.y = f2bf(v.y / dd.y);
    o.z = f2bf(v.z / dd.z); o.w = f2bf(v.w / dd.w);
    xb[i] = o;
  } else {
    int j = i - n4x;
    if (j < n4o) out[j] = make_float4(0.f, 0.f, 0.f, 0.f);
  }
}

// ---------------- kernel 3: GEMM 128x128 tile, TK=64, XOR-swizzled LDS, split-K=2 ----------------
// LDS granule g of row r holds global 16B-granule (g ^ (r&7)) -> fragment ds_read_b128
// hits 8 distinct bank groups (2-way aliasing = free), staging stays lane-contiguous.
#define TM 128
#define TN 128
#define TK 64

__launch_bounds__(256)
__global__ void gemm_bt_kernel(const u16* __restrict__ A, const u16* __restrict__ BT,
                               float* __restrict__ C, int M, int N, int K) {
  __shared__ u16 As[TM * TK];  // 16 KB
  __shared__ u16 Bs[TN * TK];  // 16 KB

  const int tid = threadIdx.x;
  const int lane = tid & 63, w = tid >> 6;
  const int wm = w >> 1, wn = w & 1;           // 2x2 wave grid, 64x64 per wave
  const int m0 = blockIdx.x * TM, n0 = blockIdx.y * TN;
  const int quad = lane >> 4, r16 = lane & 15;
  const int srow = lane >> 3;                  // staging: row within 8-row chunk
  const int sg = (lane & 7) ^ srow;            // staging: swizzled 16B granule in row

  const int kz = blockIdx.z;                   // split-K = 2
  const int Kh = K >> 1;
  const u16* Ak = A + (size_t)kz * Kh;
  const u16* Bk = BT + (size_t)kz * Kh;

  f32x4 acc[4][4] = {};

  for (int kt = 0; kt < Kh; kt += TK) {
    __syncthreads();
#pragma unroll
    for (int c = 0; c < 4; ++c) {
      int chunk = w * 4 + c;                   // 0..15, 8 rows x 64k each (1 KB)
      gld_lds16(Ak + (size_t)(m0 + chunk * 8 + srow) * K + kt + sg * 8, (char*)As + chunk * 1024);
      gld_lds16(Bk + (size_t)(n0 + chunk * 8 + srow) * K + kt + sg * 8, (char*)Bs + chunk * 1024);
    }
    __syncthreads();

#pragma unroll
    for (int ss = 0; ss < 2; ++ss) {           // two K=32 sub-steps per staged TK=64
      bf16x8 aF[4], bF[4];
#pragma unroll
      for (int mi = 0; mi < 4; ++mi) {
        int row = wm * 64 + mi * 16 + r16;
        aF[mi] = *(const bf16x8*)((const char*)As + row * 128 + (((ss * 4 + quad) ^ (row & 7)) * 16));
      }
#pragma unroll
      for (int ni = 0; ni < 4; ++ni) {
        int row = wn * 64 + ni * 16 + r16;
        bF[ni] = *(const bf16x8*)((const char*)Bs + row * 128 + (((ss * 4 + quad) ^ (row & 7)) * 16));
      }
#pragma unroll
      for (int mi = 0; mi < 4; ++mi)
#pragma unroll
        for (int ni = 0; ni < 4; ++ni)
          acc[mi][ni] = __builtin_amdgcn_mfma_f32_16x16x32_bf16(aF[mi], bF[ni], acc[mi][ni], 0, 0, 0);
    }
  }

  // epilogue: C/D layout col = lane&15, row = quad*4 + reg
#pragma unroll
  for (int mi = 0; mi < 4; ++mi)
#pragma unroll
    for (int ni = 0; ni < 4; ++ni)
#pragma unroll
      for (int r = 0; r < 4; ++r) {
        int row = m0 + wm * 64 + mi * 16 + quad * 4 + r;
        int col = n0 + wn * 64 + ni * 16 + r16;
        atomicAdd(&C[(size_t)row * N + col], acc[mi][ni][r]);
      }
}

extern "C" void kernel_launch(void* const* d_in, const int* in_sizes, int n_in,
                              void* d_out, int out_size, void* d_ws, size_t ws_size,
                              hipStream_t stream) {
  const int M = 4096, K = 4096, N = 1024;  // B, IN, OUT
  const float* x = (const float*)d_in[0];
  const float* W = (const float*)d_in[1];
  const float* U = (const float*)d_in[2];
  const float* Tp = (const float*)d_in[3];
  float* out = (float*)d_out;

  char* ws = (char*)d_ws;
  u16* xb = (u16*)ws;                                          // 32 MB
  u16* bt = (u16*)(ws + (size_t)M * K * 2);                    // 8 MB
  float* dsum = (float*)(ws + (size_t)M * K * 2 + (size_t)N * K * 2);  // 16 KB

  hipMemsetAsync(dsum, 0, K * sizeof(float), stream);
  trans_exp_kernel<<<dim3(K / 64, N / 64), 256, 0, stream>>>(W, U, Tp, bt, dsum);
  const int n4x = M * K / 4, n4o = M * N / 4;
  cast_zero_kernel<<<dim3((n4x + n4o) / 256), 256, 0, stream>>>(
      (const float4*)x, (const float4*)dsum, (ushort4*)xb, (float4*)out, n4x, n4o);
  gemm_bt_kernel<<<dim3(M / TM, N / TN, 2), 256, 0, stream>>>(xb, bt, out, M, N, K);
}